// Round 1
// baseline (18931.755 us; speedup 1.0000x reference)
//
#include <hip/hip_runtime.h>
#include <math.h>

#define BATCH 64
#define HID   1024
#define TLEN  512
#define VOC   128
#define NBLK  136
#define LDSK  1032  // padded LDS row stride in elements (+8 -> <=2-way bank alias, free)

typedef __bf16 bf16_t;
typedef __attribute__((ext_vector_type(8))) __bf16 bf16x8;
typedef __attribute__((ext_vector_type(4))) float  f32x4;

__device__ __forceinline__ float sigmoid_fast(float x) {
  return 1.0f / (1.0f + __expf(-x));
}
__device__ __forceinline__ float tanh_fast(float x) {
  float e = __expf(-2.0f * x);
  return (1.0f - e) / (1.0f + e);
}

// Device-wide sense-reversing barrier (agent scope). All NBLK blocks are
// co-resident (136 blocks, 49.6KB LDS, 256 thr -> >=1 block/CU guaranteed).
__device__ __forceinline__ void gbar(unsigned* cnt, unsigned* gen) {
  __syncthreads();
  if (threadIdx.x == 0) {
    unsigned g = __hip_atomic_load(gen, __ATOMIC_RELAXED, __HIP_MEMORY_SCOPE_AGENT);
    unsigned a = __hip_atomic_fetch_add(cnt, 1u, __ATOMIC_ACQ_REL, __HIP_MEMORY_SCOPE_AGENT);
    if (a == NBLK - 1) {
      __hip_atomic_store(cnt, 0u, __ATOMIC_RELAXED, __HIP_MEMORY_SCOPE_AGENT);
      __hip_atomic_store(gen, g + 1u, __ATOMIC_RELEASE, __HIP_MEMORY_SCOPE_AGENT);
    } else {
      while (__hip_atomic_load(gen, __ATOMIC_ACQUIRE, __HIP_MEMORY_SCOPE_AGENT) == g) {
        __builtin_amdgcn_s_sleep(1);
      }
    }
  }
  __syncthreads();
}

// A-rows (64 x HID bf16, row-major) x LDS-resident W^T slice -> one 16x16 tile
// per wave. A-frag: A[m=lane&15][k = kk*32 + (lane>>4)*8 + j]; B-frag same
// pattern on W^T rows. C/D: col = lane&15, row = (lane>>4)*4 + reg.
__device__ __forceinline__ f32x4 mm_rows(const bf16_t* __restrict__ arows,
                                         const bf16_t* __restrict__ brow) {
  f32x4 acc = {0.f, 0.f, 0.f, 0.f};
#pragma unroll 8
  for (int kk = 0; kk < 32; ++kk) {
    bf16x8 a = *reinterpret_cast<const bf16x8*>(arows + kk * 32);
    bf16x8 b = *reinterpret_cast<const bf16x8*>(brow + kk * 32);
    acc = __builtin_amdgcn_mfma_f32_16x16x32_bf16(a, b, acc, 0, 0, 0);
  }
  return acc;
}

__global__ void __launch_bounds__(256)
gru_persistent(const int* __restrict__ X,
               const float* __restrict__ Wr_x, const float* __restrict__ Wr_h, const float* __restrict__ b_r,
               const float* __restrict__ Wz_x, const float* __restrict__ Wz_h, const float* __restrict__ b_z,
               const float* __restrict__ Wh_x, const float* __restrict__ Wh_h, const float* __restrict__ b_h,
               const float* __restrict__ W_o,  const float* __restrict__ b_o,
               float* __restrict__ out,
               float* __restrict__ h_f32, bf16_t* __restrict__ h_bf,
               float* __restrict__ z_f32, bf16_t* __restrict__ rh_bf,
               unsigned* __restrict__ bar)
{
  __shared__ __align__(16) bf16_t WtA[16 * LDSK];  // stage-A W^T slice (bf16)
  __shared__ __align__(16) bf16_t WtB[8 * LDSK];   // stage-B Wh_h^T slice
  __shared__ float bAs[16];

  const int blk  = blockIdx.x;
  const int tid  = threadIdx.x;
  const int lane = tid & 63;
  const int wv   = tid >> 6;       // wave 0..3 -> batch tile wv*16..
  const int n16  = lane & 15;      // A-row / B-col / D-col index
  const int q    = lane >> 4;      // quad -> k-subchunk / D-row group

  const bool isR   = (blk < 64);
  const bool isZ   = (blk >= 64 && blk < 128);
  const bool isOut = (blk >= 128);

  // ---- one-time: stage weight slices into LDS, transposed + bf16 ----
  const float* WsrcA; int rsA, c0A; const float* biasA;
  if (isR)      { WsrcA = Wr_h; rsA = HID; c0A = blk * 16;         biasA = b_r; }
  else if (isZ) { WsrcA = Wz_h; rsA = HID; c0A = (blk - 64) * 16;  biasA = b_z; }
  else          { WsrcA = W_o;  rsA = VOC; c0A = (blk - 128) * 16; biasA = b_o; }
  for (int idx = tid; idx < 16 * HID; idx += 256) {
    int n = idx & 15, k = idx >> 4;
    WtA[n * LDSK + k] = (bf16_t)WsrcA[k * rsA + c0A + n];
  }
  if (!isOut) {
    const int jB0 = blk * 8;
    for (int idx = tid; idx < 8 * HID; idx += 256) {
      int n = idx & 7, k = idx >> 3;
      WtB[n * LDSK + k] = (bf16_t)Wh_h[k * HID + jB0 + n];
    }
  }
  if (tid < 16) bAs[tid] = biasA[c0A + tid];
  __syncthreads();

  unsigned* cnt = bar;
  unsigned* gen = bar + 1;

  const bf16_t* h_arow  = h_bf  + (wv * 16 + n16) * HID + q * 8;
  const bf16_t* rh_arow = rh_bf + (wv * 16 + n16) * HID + q * 8;
  const bf16_t* wA_brow = &WtA[n16 * LDSK + q * 8];
  const bf16_t* wB_brow = &WtB[(n16 & 7) * LDSK + q * 8];

  for (int t = 0; t < TLEN; ++t) {
    // ================= stage A: r, z (step t) + out (step t-1) =============
    if (!isOut) {
      f32x4 acc = mm_rows(h_arow, wA_brow);
      const float* Wgx = isR ? Wr_x : Wz_x;
      const int j = c0A + n16;
#pragma unroll
      for (int i = 0; i < 4; ++i) {
        int b  = wv * 16 + q * 4 + i;
        int xb = X[b * TLEN + t];
        float pre = acc[i] + bAs[n16] + Wgx[xb * HID + j];
        float g = sigmoid_fast(pre);
        if (isR) {
          rh_bf[b * HID + j] = (bf16_t)(g * h_f32[b * HID + j]);
        } else {
          z_f32[b * HID + j] = g;
        }
      }
    } else if (t > 0) {
      f32x4 acc = mm_rows(h_arow, wA_brow);  // out_{t-1} = h_t @ W_o
      const int v = c0A + n16;
#pragma unroll
      for (int i = 0; i < 4; ++i) {
        int b = wv * 16 + q * 4 + i;
        out[(b * TLEN + (t - 1)) * VOC + v] = acc[i] + bAs[n16];
      }
    }
    gbar(cnt, gen);

    // ================= stage B: h_tilde, h_new =============================
    if (!isOut) {
      f32x4 acc = mm_rows(rh_arow, wB_brow);
      if (n16 < 8) {  // cols 8..15 are aliased garbage, discard
        const int j = blk * 8 + n16;
#pragma unroll
        for (int i = 0; i < 4; ++i) {
          int b  = wv * 16 + q * 4 + i;
          int xb = X[b * TLEN + t];
          float pre = acc[i] + b_h[j] + Wh_x[xb * HID + j];
          float ht  = tanh_fast(pre);
          float zz  = z_f32[b * HID + j];
          float h0  = h_f32[b * HID + j];
          float hn  = zz * h0 + (1.f - zz) * ht;
          h_f32[b * HID + j] = hn;
          h_bf[b * HID + j]  = (bf16_t)hn;
        }
      }
    }
    gbar(cnt, gen);
  }

  // ================= epilogue: out_{T-1} = h_T @ W_o =======================
  if (isOut) {
    f32x4 acc = mm_rows(h_arow, wA_brow);
    const int v = c0A + n16;
#pragma unroll
    for (int i = 0; i < 4; ++i) {
      int b = wv * 16 + q * 4 + i;
      out[(b * TLEN + (TLEN - 1)) * VOC + v] = acc[i] + bAs[n16];
    }
  }
}

extern "C" void kernel_launch(void* const* d_in, const int* in_sizes, int n_in,
                              void* d_out, int out_size, void* d_ws, size_t ws_size,
                              hipStream_t stream) {
  const int*   X    = (const int*)d_in[0];
  const float* Wr_x = (const float*)d_in[1];
  const float* Wr_h = (const float*)d_in[2];
  const float* b_r  = (const float*)d_in[3];
  const float* Wz_x = (const float*)d_in[4];
  const float* Wz_h = (const float*)d_in[5];
  const float* b_z  = (const float*)d_in[6];
  const float* Wh_x = (const float*)d_in[7];
  const float* Wh_h = (const float*)d_in[8];
  const float* b_h  = (const float*)d_in[9];
  const float* W_o  = (const float*)d_in[10];
  const float* b_o  = (const float*)d_in[11];

  char* ws = (char*)d_ws;
  // layout: [bar 256B | h_f32 256KB | h_bf 128KB | z_f32 256KB | rh_bf 128KB]
  unsigned* bar   = (unsigned*)ws;
  float*    h_f32 = (float*)(ws + 256);
  bf16_t*   h_bf  = (bf16_t*)(ws + 256 + 262144);
  float*    z_f32 = (float*)(ws + 256 + 262144 + 131072);
  bf16_t*   rh_bf = (bf16_t*)(ws + 256 + 262144 + 131072 + 262144);

  // zero barrier + h0 (z/rh are written before read every step)
  hipMemsetAsync(ws, 0, 256 + 262144 + 131072, stream);

  gru_persistent<<<NBLK, 256, 0, stream>>>(
      X, Wr_x, Wr_h, b_r, Wz_x, Wz_h, b_z, Wh_x, Wh_h, b_h, W_o, b_o,
      (float*)d_out, h_f32, h_bf, z_f32, rh_bf, bar);
}

// Round 2
// 13140.460 us; speedup vs baseline: 1.4407x; 1.4407x over previous
//
#include <hip/hip_runtime.h>
#include <math.h>

#define HID   1024
#define TLEN  512
#define VOC   128
#define NWORK 64          // worker blocks: 16 hidden cols each, all 3 gates
#define NOUT  8           // out-head blocks: 16 vocab cols each
#define NBLK  (NWORK + NOUT)
#define LDSK  1032        // padded row stride (16B-aligned rows, 2-way bank alias = free)
#define FSTR  16          // flag stride in uints (64B)

typedef __bf16 bf16_t;
typedef __attribute__((ext_vector_type(8))) __bf16 bf16x8;
typedef __attribute__((ext_vector_type(4))) float  f32x4;

__device__ __forceinline__ float sigmoid_fast(float x) {
  return 1.0f / (1.0f + __expf(-x));
}
__device__ __forceinline__ float tanh_fast(float x) {
  float e = __expf(-2.0f * x);
  return (1.0f - e) / (1.0f + e);
}

union FragU { unsigned long long u[2]; bf16x8 v; };

// coherent (agent-scope, cache-bypassing) 16B fragment load, as 2x8B relaxed atomics
__device__ __forceinline__ bf16x8 ld_frag(const bf16_t* p) {
  FragU x;
  x.u[0] = __hip_atomic_load((const unsigned long long*)p,       __ATOMIC_RELAXED, __HIP_MEMORY_SCOPE_AGENT);
  x.u[1] = __hip_atomic_load((const unsigned long long*)(p + 4), __ATOMIC_RELAXED, __HIP_MEMORY_SCOPE_AGENT);
  return x.v;
}

__device__ __forceinline__ void st_bf(bf16_t* p, float f) {
  union { bf16_t b; unsigned short s; } c;
  c.b = (bf16_t)f;
  __hip_atomic_store((unsigned short*)p, c.s, __ATOMIC_RELAXED, __HIP_MEMORY_SCOPE_AGENT);
}

// all-wave spin until flags[i*FSTR] >= tgt for i in [0,n). One relaxed load per
// lane per poll; single acquire fence on exit.
__device__ __forceinline__ void wait_ge(const unsigned* flags, int n, unsigned tgt) {
  const int lane = threadIdx.x & 63;
  for (;;) {
    unsigned g = tgt;
    if (lane < n)
      g = __hip_atomic_load(&flags[lane * FSTR], __ATOMIC_RELAXED, __HIP_MEMORY_SCOPE_AGENT);
    if (__all(g >= tgt)) break;
    __builtin_amdgcn_s_sleep(1);
  }
  __builtin_amdgcn_fence(__ATOMIC_ACQUIRE, "agent");
}

// block-wide publish: __syncthreads drains all waves' vmcnt (stores complete),
// then one release store of the flag.
__device__ __forceinline__ void publish(unsigned* f, unsigned v) {
  __syncthreads();
  if (threadIdx.x == 0)
    __hip_atomic_store(f, v, __ATOMIC_RELEASE, __HIP_MEMORY_SCOPE_AGENT);
}

__global__ void __launch_bounds__(256)
gru_fg(const int* __restrict__ X,
       const float* __restrict__ Wr_x, const float* __restrict__ Wr_h, const float* __restrict__ b_r,
       const float* __restrict__ Wz_x, const float* __restrict__ Wz_h, const float* __restrict__ b_z,
       const float* __restrict__ Wh_x, const float* __restrict__ Wh_h, const float* __restrict__ b_h,
       const float* __restrict__ W_o,  const float* __restrict__ b_o,
       float* __restrict__ out,
       bf16_t* __restrict__ h_bf, bf16_t* __restrict__ rh_bf,
       unsigned* __restrict__ h_flag, unsigned* __restrict__ rh_flag, unsigned* __restrict__ out_flag)
{
  __shared__ __align__(16) bf16_t W0[16 * LDSK];
  __shared__ __align__(16) bf16_t W1[16 * LDSK];
  __shared__ __align__(16) bf16_t W2[16 * LDSK];

  const int blk  = blockIdx.x;
  const int tid  = threadIdx.x;
  const int lane = tid & 63;
  const int wv   = tid >> 6;     // wave -> batch tile [wv*16, +16)
  const int n16  = lane & 15;    // A-row (batch) for A-frag / column for B-frag & D
  const int q    = lane >> 4;    // k-subchunk / D-row quad

  if (blk < NWORK) {
    // ================= worker: 16 cols of r, z, h_tilde =================
    const int c0 = blk * 16;
    for (int idx = tid; idx < 16 * HID; idx += 256) {
      int n = idx & 15, k = idx >> 4;
      W0[n * LDSK + k] = (bf16_t)Wr_h[k * HID + c0 + n];
      W1[n * LDSK + k] = (bf16_t)Wz_h[k * HID + c0 + n];
      W2[n * LDSK + k] = (bf16_t)Wh_h[k * HID + c0 + n];
    }
    __syncthreads();

    const int j = c0 + n16;
    const float brs = b_r[j], bzs = b_z[j], bhs = b_h[j];
    const bf16_t* hrow  = h_bf  + (wv * 16 + n16) * HID + q * 8;
    const bf16_t* rhrow = rh_bf + (wv * 16 + n16) * HID + q * 8;
    const bf16_t* w0r = &W0[n16 * LDSK + q * 8];
    const bf16_t* w1r = &W1[n16 * LDSK + q * 8];
    const bf16_t* w2r = &W2[n16 * LDSK + q * 8];

    f32x4 h_loc = {0.f, 0.f, 0.f, 0.f};   // h[b, j] fp32 master (D-tile layout)

    for (int t = 0; t < TLEN; ++t) {
      // ---- stage A: r and z for our cols; write rh ----
      wait_ge(h_flag, NWORK, (unsigned)t);
      f32x4 aR = {0.f, 0.f, 0.f, 0.f}, aZ = {0.f, 0.f, 0.f, 0.f};
#pragma unroll 8
      for (int kk = 0; kk < 32; ++kk) {
        bf16x8 a  = ld_frag(hrow + kk * 32);
        bf16x8 br = *reinterpret_cast<const bf16x8*>(w0r + kk * 32);
        bf16x8 bz = *reinterpret_cast<const bf16x8*>(w1r + kk * 32);
        aR = __builtin_amdgcn_mfma_f32_16x16x32_bf16(a, br, aR, 0, 0, 0);
        aZ = __builtin_amdgcn_mfma_f32_16x16x32_bf16(a, bz, aZ, 0, 0, 0);
      }
      int xb[4];
      f32x4 z_loc;
#pragma unroll
      for (int i = 0; i < 4; ++i) {
        int b = wv * 16 + q * 4 + i;
        xb[i] = X[b * TLEN + t];
        float r = sigmoid_fast(aR[i] + brs + Wr_x[xb[i] * HID + j]);
        st_bf(rh_bf + b * HID + j, r * h_loc[i]);
        z_loc[i] = sigmoid_fast(aZ[i] + bzs + Wz_x[xb[i] * HID + j]);
      }
      publish(&rh_flag[blk * FSTR], (unsigned)(t + 1));

      // ---- stage B: h_tilde, h_new ----
      wait_ge(rh_flag, NWORK, (unsigned)(t + 1));
      f32x4 aH = {0.f, 0.f, 0.f, 0.f};
#pragma unroll 8
      for (int kk = 0; kk < 32; ++kk) {
        bf16x8 a  = ld_frag(rhrow + kk * 32);
        bf16x8 bh = *reinterpret_cast<const bf16x8*>(w2r + kk * 32);
        aH = __builtin_amdgcn_mfma_f32_16x16x32_bf16(a, bh, aH, 0, 0, 0);
      }
      // out-head blocks must be done reading h_t before we overwrite it
      for (;;) {
        unsigned g = (unsigned)t;
        if (lane < NOUT)
          g = __hip_atomic_load(&out_flag[lane * FSTR], __ATOMIC_RELAXED, __HIP_MEMORY_SCOPE_AGENT);
        if (__all(g >= (unsigned)t)) break;
        __builtin_amdgcn_s_sleep(1);
      }
#pragma unroll
      for (int i = 0; i < 4; ++i) {
        int b = wv * 16 + q * 4 + i;
        float ht = tanh_fast(aH[i] + bhs + Wh_x[xb[i] * HID + j]);
        float hn = z_loc[i] * h_loc[i] + (1.f - z_loc[i]) * ht;
        h_loc[i] = hn;
        st_bf(h_bf + b * HID + j, hn);
      }
      publish(&h_flag[blk * FSTR], (unsigned)(t + 1));
    }
  } else {
    // ================= out head: out[t-1] = h_t @ W_o + b_o =================
    const int c0 = (blk - NWORK) * 16;
    for (int idx = tid; idx < 16 * HID; idx += 256) {
      int n = idx & 15, k = idx >> 4;
      W0[n * LDSK + k] = (bf16_t)W_o[k * VOC + c0 + n];
    }
    __syncthreads();

    const int v = c0 + n16;
    const float bos = b_o[v];
    const bf16_t* hrow = h_bf + (wv * 16 + n16) * HID + q * 8;
    const bf16_t* w0r  = &W0[n16 * LDSK + q * 8];

    for (int t = 1; t <= TLEN; ++t) {
      wait_ge(h_flag, NWORK, (unsigned)t);
      f32x4 acc = {0.f, 0.f, 0.f, 0.f};
#pragma unroll 8
      for (int kk = 0; kk < 32; ++kk) {
        bf16x8 a = ld_frag(hrow + kk * 32);
        bf16x8 b = *reinterpret_cast<const bf16x8*>(w0r + kk * 32);
        acc = __builtin_amdgcn_mfma_f32_16x16x32_bf16(a, b, acc, 0, 0, 0);
      }
#pragma unroll
      for (int i = 0; i < 4; ++i) {
        int b = wv * 16 + q * 4 + i;
        out[(b * TLEN + (t - 1)) * VOC + v] = acc[i] + bos;
      }
      publish(&out_flag[(blk - NWORK) * FSTR], (unsigned)t);  // done reading h_t
    }
  }
}

extern "C" void kernel_launch(void* const* d_in, const int* in_sizes, int n_in,
                              void* d_out, int out_size, void* d_ws, size_t ws_size,
                              hipStream_t stream) {
  const int*   X    = (const int*)d_in[0];
  const float* Wr_x = (const float*)d_in[1];
  const float* Wr_h = (const float*)d_in[2];
  const float* b_r  = (const float*)d_in[3];
  const float* Wz_x = (const float*)d_in[4];
  const float* Wz_h = (const float*)d_in[5];
  const float* b_z  = (const float*)d_in[6];
  const float* Wh_x = (const float*)d_in[7];
  const float* Wh_h = (const float*)d_in[8];
  const float* b_h  = (const float*)d_in[9];
  const float* W_o  = (const float*)d_in[10];
  const float* b_o  = (const float*)d_in[11];

  char* ws = (char*)d_ws;
  // layout: [h_flag 4KB | rh_flag 4KB | out_flag 0.5KB pad->8KB | h_bf 128KB | rh_bf 128KB]
  unsigned* h_flag   = (unsigned*)(ws);
  unsigned* rh_flag  = (unsigned*)(ws + 4096);
  unsigned* out_flag = (unsigned*)(ws + 8192);
  bf16_t*   h_bf     = (bf16_t*)(ws + 16384);
  bf16_t*   rh_bf    = (bf16_t*)(ws + 16384 + 131072);

  // zero flags + h0 (rh is written before read every step)
  hipMemsetAsync(ws, 0, 16384 + 131072, stream);

  gru_fg<<<NBLK, 256, 0, stream>>>(
      X, Wr_x, Wr_h, b_r, Wz_x, Wz_h, b_z, Wh_x, Wh_h, b_h, W_o, b_o,
      (float*)d_out, h_bf, rh_bf, h_flag, rh_flag, out_flag);
}

// Round 3
// 12949.025 us; speedup vs baseline: 1.4620x; 1.0148x over previous
//
#include <hip/hip_runtime.h>

#define HID   1024
#define TLEN  512
#define VOC   128
#define NWORK 64          // worker blocks: 16 hidden cols each, all 3 gates
#define NOUT  8           // out-head blocks: 16 vocab cols each
#define NBLK  (NWORK + NOUT)
#define LDSK  1032        // padded row stride (16B-aligned rows)
#define HBUF  (64 * HID)  // one h buffer (elements)
#define NHB   4           // h buffer depth

typedef __bf16 bf16_t;
typedef __attribute__((ext_vector_type(8))) __bf16 bf16x8;
typedef __attribute__((ext_vector_type(4))) float  f32x4;

__device__ __forceinline__ float sigmoid_fast(float x) {
  return 1.0f / (1.0f + __expf(-x));
}
__device__ __forceinline__ float tanh_fast(float x) {
  float e = __expf(-2.0f * x);
  return (1.0f - e) / (1.0f + e);
}

union FragU { unsigned long long u[2]; bf16x8 v; };

// coherence-point (agent-scope) 16B fragment load as 2x8B relaxed atomics
__device__ __forceinline__ bf16x8 ld_frag(const bf16_t* p) {
  FragU x;
  x.u[0] = __hip_atomic_load((const unsigned long long*)p,       __ATOMIC_RELAXED, __HIP_MEMORY_SCOPE_AGENT);
  x.u[1] = __hip_atomic_load((const unsigned long long*)(p + 4), __ATOMIC_RELAXED, __HIP_MEMORY_SCOPE_AGENT);
  return x.v;
}

__device__ __forceinline__ void st_bf(bf16_t* p, float f) {
  union { bf16_t b; unsigned short s; } c;
  c.b = (bf16_t)f;
  __hip_atomic_store((unsigned short*)p, c.s, __ATOMIC_RELAXED, __HIP_MEMORY_SCOPE_AGENT);
}

// wave 0 polls n packed flags (4B stride) with one coalesced load; other waves
// park in s_barrier. No acquire fence: all cross-block data is read via
// coherence-point atomics, ordered after the flag observation by the branch.
__device__ __forceinline__ void wait64(const unsigned* flags, int n, unsigned tgt) {
  if ((threadIdx.x >> 6) == 0) {
    const int lane = threadIdx.x & 63;
    for (;;) {
      unsigned g = tgt;
      if (lane < n)
        g = __hip_atomic_load(&flags[lane], __ATOMIC_RELAXED, __HIP_MEMORY_SCOPE_AGENT);
      if (__all(g >= tgt)) break;
      __builtin_amdgcn_s_sleep(1);
    }
  }
  __syncthreads();
}

// stage-B wait: all rh flags >= tgt AND all out flags >= otgt
__device__ __forceinline__ void wait_rh_out(const unsigned* rfl, const unsigned* ofl,
                                            unsigned tgt, unsigned otgt) {
  if ((threadIdx.x >> 6) == 0) {
    const int lane = threadIdx.x & 63;
    for (;;) {
      unsigned g = tgt, g2 = otgt;
      if (lane < NWORK)
        g = __hip_atomic_load(&rfl[lane], __ATOMIC_RELAXED, __HIP_MEMORY_SCOPE_AGENT);
      if (lane < NOUT)
        g2 = __hip_atomic_load(&ofl[lane], __ATOMIC_RELAXED, __HIP_MEMORY_SCOPE_AGENT);
      if (__all(g >= tgt && g2 >= otgt)) break;
      __builtin_amdgcn_s_sleep(1);
    }
  }
  __syncthreads();
}

// publish: __syncthreads drains every wave's stores (vmcnt(0) before s_barrier),
// then one release store of the flag.
__device__ __forceinline__ void publish(unsigned* f, unsigned v) {
  __syncthreads();
  if (threadIdx.x == 0)
    __hip_atomic_store(f, v, __ATOMIC_RELEASE, __HIP_MEMORY_SCOPE_AGENT);
}

__global__ void __launch_bounds__(256)
gru_fg(const int* __restrict__ X,
       const float* __restrict__ Wr_x, const float* __restrict__ Wr_h, const float* __restrict__ b_r,
       const float* __restrict__ Wz_x, const float* __restrict__ Wz_h, const float* __restrict__ b_z,
       const float* __restrict__ Wh_x, const float* __restrict__ Wh_h, const float* __restrict__ b_h,
       const float* __restrict__ W_o,  const float* __restrict__ b_o,
       float* __restrict__ out,
       bf16_t* __restrict__ h0, bf16_t* __restrict__ rh_bf,
       unsigned* __restrict__ flags)
{
  __shared__ __align__(16) bf16_t W0[16 * LDSK];
  __shared__ __align__(16) bf16_t W1[16 * LDSK];
  __shared__ __align__(16) bf16_t W2[16 * LDSK];

  unsigned* hfl = flags;        // [0,64)  h_flag
  unsigned* rfl = flags + 64;   // [64,128) rh_flag
  unsigned* ofl = flags + 128;  // [128,136) out_flag

  const int blk  = blockIdx.x;
  const int tid  = threadIdx.x;
  const int lane = tid & 63;
  const int wv   = tid >> 6;     // wave -> batch tile [wv*16, +16)
  const int n16  = lane & 15;    // A-row (batch) / B-col / D-col
  const int q    = lane >> 4;    // k-subchunk / D-row quad

  const int aoff = (wv * 16 + n16) * HID + q * 8;  // A-frag offset in h/rh

  if (blk < NWORK) {
    // ================= worker: 16 cols of r, z, h_tilde =================
    const int c0 = blk * 16;
    for (int idx = tid; idx < 16 * HID; idx += 256) {
      int n = idx & 15, k = idx >> 4;
      W0[n * LDSK + k] = (bf16_t)Wr_h[k * HID + c0 + n];
      W1[n * LDSK + k] = (bf16_t)Wz_h[k * HID + c0 + n];
      W2[n * LDSK + k] = (bf16_t)Wh_h[k * HID + c0 + n];
    }
    __syncthreads();

    const int j = c0 + n16;
    const float brs = b_r[j], bzs = b_z[j], bhs = b_h[j];
    const bf16_t* rhrow = rh_bf + aoff;
    const bf16_t* w0r = &W0[n16 * LDSK + q * 8];
    const bf16_t* w1r = &W1[n16 * LDSK + q * 8];
    const bf16_t* w2r = &W2[n16 * LDSK + q * 8];

    int bi[4];
#pragma unroll
    for (int i = 0; i < 4; ++i) bi[i] = wv * 16 + q * 4 + i;

    f32x4 h_loc = {0.f, 0.f, 0.f, 0.f};   // h[b, j] fp32 master (D-tile layout)

    for (int t = 0; t < TLEN; ++t) {
      // ---- stage A: r and z for our cols; write rh ----
      wait64(hfl, NWORK, (unsigned)t);
      const bf16_t* hrow = h0 + (t & (NHB - 1)) * HBUF + aoff;
      f32x4 aR = {0.f, 0.f, 0.f, 0.f}, aZ = {0.f, 0.f, 0.f, 0.f};
#pragma unroll 8
      for (int kk = 0; kk < 32; ++kk) {
        bf16x8 a  = ld_frag(hrow + kk * 32);
        bf16x8 br = *reinterpret_cast<const bf16x8*>(w0r + kk * 32);
        bf16x8 bz = *reinterpret_cast<const bf16x8*>(w1r + kk * 32);
        aR = __builtin_amdgcn_mfma_f32_16x16x32_bf16(a, br, aR, 0, 0, 0);
        aZ = __builtin_amdgcn_mfma_f32_16x16x32_bf16(a, bz, aZ, 0, 0, 0);
      }
      int xb[4];
      f32x4 z_loc;
#pragma unroll
      for (int i = 0; i < 4; ++i) {
        xb[i] = X[bi[i] * TLEN + t];
        float r = sigmoid_fast(aR[i] + brs + Wr_x[xb[i] * HID + j]);
        st_bf(rh_bf + bi[i] * HID + j, r * h_loc[i]);
        z_loc[i] = sigmoid_fast(aZ[i] + bzs + Wz_x[xb[i] * HID + j]);
      }
      publish(&rfl[blk], (unsigned)(t + 1));

      // ---- stage B: h_tilde, h_new ----
      unsigned otgt = (t >= 3) ? (unsigned)(t - 3) : 0u;  // h buf WAR vs out heads
      wait_rh_out(rfl, ofl, (unsigned)(t + 1), otgt);
      f32x4 aH = {0.f, 0.f, 0.f, 0.f};
#pragma unroll 8
      for (int kk = 0; kk < 32; ++kk) {
        bf16x8 a  = ld_frag(rhrow + kk * 32);
        bf16x8 bh = *reinterpret_cast<const bf16x8*>(w2r + kk * 32);
        aH = __builtin_amdgcn_mfma_f32_16x16x32_bf16(a, bh, aH, 0, 0, 0);
      }
      bf16_t* hnext = h0 + ((t + 1) & (NHB - 1)) * HBUF;
#pragma unroll
      for (int i = 0; i < 4; ++i) {
        float ht = tanh_fast(aH[i] + bhs + Wh_x[xb[i] * HID + j]);
        float hn = z_loc[i] * h_loc[i] + (1.f - z_loc[i]) * ht;
        h_loc[i] = hn;
        st_bf(hnext + bi[i] * HID + j, hn);
      }
      publish(&hfl[blk], (unsigned)(t + 1));
    }
  } else {
    // ================= out head: out[t-1] = h_t @ W_o + b_o =================
    const int ob = blk - NWORK;
    const int c0 = ob * 16;
    for (int idx = tid; idx < 16 * HID; idx += 256) {
      int n = idx & 15, k = idx >> 4;
      W0[n * LDSK + k] = (bf16_t)W_o[k * VOC + c0 + n];
    }
    __syncthreads();

    const int v = c0 + n16;
    const float bos = b_o[v];
    const bf16_t* w0r = &W0[n16 * LDSK + q * 8];

    for (int t = 1; t <= TLEN; ++t) {
      wait64(hfl, NWORK, (unsigned)t);
      const bf16_t* hrow = h0 + (t & (NHB - 1)) * HBUF + aoff;
      f32x4 acc = {0.f, 0.f, 0.f, 0.f};
#pragma unroll 8
      for (int kk = 0; kk < 32; ++kk) {
        bf16x8 a = ld_frag(hrow + kk * 32);
        bf16x8 b = *reinterpret_cast<const bf16x8*>(w0r + kk * 32);
        acc = __builtin_amdgcn_mfma_f32_16x16x32_bf16(a, b, acc, 0, 0, 0);
      }
      publish(&ofl[ob], (unsigned)t);  // h_t reads complete (acc consumed loads)
#pragma unroll
      for (int i = 0; i < 4; ++i) {
        int b = wv * 16 + q * 4 + i;
        out[(b * TLEN + (t - 1)) * VOC + v] = acc[i] + bos;
      }
    }
  }
}

extern "C" void kernel_launch(void* const* d_in, const int* in_sizes, int n_in,
                              void* d_out, int out_size, void* d_ws, size_t ws_size,
                              hipStream_t stream) {
  const int*   X    = (const int*)d_in[0];
  const float* Wr_x = (const float*)d_in[1];
  const float* Wr_h = (const float*)d_in[2];
  const float* b_r  = (const float*)d_in[3];
  const float* Wz_x = (const float*)d_in[4];
  const float* Wz_h = (const float*)d_in[5];
  const float* b_z  = (const float*)d_in[6];
  const float* Wh_x = (const float*)d_in[7];
  const float* Wh_h = (const float*)d_in[8];
  const float* b_h  = (const float*)d_in[9];
  const float* W_o  = (const float*)d_in[10];
  const float* b_o  = (const float*)d_in[11];

  char* ws = (char*)d_ws;
  // layout: [flags 4KB | h_bf 4 x 128KB | rh_bf 128KB]
  unsigned* flags = (unsigned*)ws;
  bf16_t*   h0    = (bf16_t*)(ws + 4096);
  bf16_t*   rh_bf = (bf16_t*)(ws + 4096 + NHB * HBUF * sizeof(bf16_t));

  // zero flags + h buffer 0 (h(0) = 0); rh written before read each step
  hipMemsetAsync(ws, 0, 4096 + HBUF * sizeof(bf16_t), stream);

  gru_fg<<<NBLK, 256, 0, stream>>>(
      X, Wr_x, Wr_h, b_r, Wz_x, Wz_h, b_z, Wh_x, Wh_h, b_h, W_o, b_o,
      (float*)d_out, h0, rh_bf, flags);
}

// Round 4
// 8677.898 us; speedup vs baseline: 2.1816x; 1.4922x over previous
//
#include <hip/hip_runtime.h>

#define HID   1024
#define TLEN  512
#define VOC   128
#define NR    32          // reset-gate blocks: 32 cols each (r, rh)
#define NZ    32          // update blocks: 32 cols each (z, h_tilde, h_new)
#define NO    8           // out-head blocks: 16 vocab cols each
#define NBLK  (NR + NZ + NO)
#define LDSK  1032        // padded LDS row stride (16B-aligned rows)
#define HBUF  (64 * HID)  // one h buffer (elements)
#define NHB   4           // h buffer rotation depth

typedef __bf16 bf16_t;
typedef __attribute__((ext_vector_type(8))) __bf16 bf16x8;
typedef __attribute__((ext_vector_type(4))) float  f32x4;

__device__ __forceinline__ float sigmoid_fast(float x) {
  return 1.0f / (1.0f + __expf(-x));
}
__device__ __forceinline__ float tanh_fast(float x) {
  float e = __expf(-2.0f * x);
  return (1.0f - e) / (1.0f + e);
}

// wave 0 polls 32 packed flags; on success an agent acquire fence
// (buffer_inv: invalidates L1 + this XCD's L2) makes producers' cached
// stores visible to the plain loads that follow. Other waves park at the
// barrier; the shared-cache invalidate covers them too.
__device__ __forceinline__ void wait32(const unsigned* flags, unsigned tgt) {
  if ((threadIdx.x >> 6) == 0) {
    const int lane = threadIdx.x & 63;
    for (;;) {
      unsigned g = tgt;
      if (lane < 32)
        g = __hip_atomic_load(&flags[lane], __ATOMIC_RELAXED, __HIP_MEMORY_SCOPE_AGENT);
      if (__all(g >= tgt)) break;
      __builtin_amdgcn_s_sleep(1);
    }
    __builtin_amdgcn_fence(__ATOMIC_ACQUIRE, "agent");
  }
  __syncthreads();
}

// combined wait: rfl[0..32) >= tgt (lanes 0..31) AND ofl[0..8) >= otgt (lanes 32..39)
__device__ __forceinline__ void wait_rf_of(const unsigned* rfl, const unsigned* ofl,
                                           unsigned tgt, unsigned otgt) {
  if ((threadIdx.x >> 6) == 0) {
    const int lane = threadIdx.x & 63;
    for (;;) {
      bool ok = true;
      if (lane < 32)
        ok = __hip_atomic_load(&rfl[lane], __ATOMIC_RELAXED, __HIP_MEMORY_SCOPE_AGENT) >= tgt;
      else if (lane < 40)
        ok = __hip_atomic_load(&ofl[lane - 32], __ATOMIC_RELAXED, __HIP_MEMORY_SCOPE_AGENT) >= otgt;
      if (__all(ok)) break;
      __builtin_amdgcn_s_sleep(1);
    }
    __builtin_amdgcn_fence(__ATOMIC_ACQUIRE, "agent");
  }
  __syncthreads();
}

// publish: barrier drains every wave's stores to L2 (compiler emits vmcnt(0)
// before s_barrier); the release store then writes back dirty L2 (buffer_wbl2)
// before the flag becomes visible at the coherence point.
__device__ __forceinline__ void publish(unsigned* f, unsigned v) {
  __syncthreads();
  if (threadIdx.x == 0)
    __hip_atomic_store(f, v, __ATOMIC_RELEASE, __HIP_MEMORY_SCOPE_AGENT);
}

__global__ void __launch_bounds__(256)
gru_split(const int* __restrict__ X,
          const float* __restrict__ Wr_x, const float* __restrict__ Wr_h, const float* __restrict__ b_r,
          const float* __restrict__ Wz_x, const float* __restrict__ Wz_h, const float* __restrict__ b_z,
          const float* __restrict__ Wh_x, const float* __restrict__ Wh_h, const float* __restrict__ b_h,
          const float* __restrict__ W_o,  const float* __restrict__ b_o,
          float* __restrict__ out,
          bf16_t* __restrict__ h0, bf16_t* __restrict__ rh_bf,
          unsigned* __restrict__ flags)
{
  __shared__ __align__(16) bf16_t Wbuf[2 * 32 * LDSK];  // 132KB

  unsigned* hfl = flags;        // [0,32)   published by ZH blocks
  unsigned* rfl = flags + 64;   // [64,96)  published by R blocks
  unsigned* ofl = flags + 128;  // [128,136) published by out heads

  const int blk  = blockIdx.x;
  const int tid  = threadIdx.x;
  const int lane = tid & 63;
  const int wv   = tid >> 6;     // wave -> batch tile [wv*16, +16)
  const int n16  = lane & 15;    // A-row(batch) / B-col / D-col within 16-tile
  const int q    = lane >> 4;    // k-subchunk / D-row quad

  const int aoff = (wv * 16 + n16) * HID + q * 8;  // A-frag offset in h/rh

  int bi[4];
#pragma unroll
  for (int i = 0; i < 4; ++i) bi[i] = wv * 16 + q * 4 + i;

  if (blk < NR) {
    // ============ R block: 32 cols of r; writes rh (line-exclusive 64B) ====
    const int c0 = blk * 32;
    for (int idx = tid; idx < 32 * HID; idx += 256) {
      int n = idx & 31, k = idx >> 5;
      Wbuf[n * LDSK + k] = (bf16_t)Wr_h[k * HID + c0 + n];
    }
    __syncthreads();

    const int j0 = c0 + n16, j1 = j0 + 16;
    const float br0 = b_r[j0], br1 = b_r[j1];
    const bf16_t* w0 = &Wbuf[n16 * LDSK + q * 8];
    const bf16_t* w1 = &Wbuf[(16 + n16) * LDSK + q * 8];

    for (int t = 0; t < TLEN; ++t) {
      wait32(hfl, (unsigned)t);
      const bf16_t* hslot = h0 + (t & (NHB - 1)) * HBUF;
      // issue gathers early (h-independent) so they overlap the MFMA chain
      int xb[4]; float gx0[4], gx1[4];
#pragma unroll
      for (int i = 0; i < 4; ++i) {
        xb[i]  = X[bi[i] * TLEN + t];
        gx0[i] = Wr_x[xb[i] * HID + j0];
        gx1[i] = Wr_x[xb[i] * HID + j1];
      }
      const bf16_t* hrow = hslot + aoff;
      f32x4 a0 = {0.f,0.f,0.f,0.f}, a1 = {0.f,0.f,0.f,0.f};
#pragma unroll 8
      for (int kk = 0; kk < 32; ++kk) {
        bf16x8 a  = *reinterpret_cast<const bf16x8*>(hrow + kk * 32);
        bf16x8 b0 = *reinterpret_cast<const bf16x8*>(w0 + kk * 32);
        bf16x8 b1 = *reinterpret_cast<const bf16x8*>(w1 + kk * 32);
        a0 = __builtin_amdgcn_mfma_f32_16x16x32_bf16(a, b0, a0, 0, 0, 0);
        a1 = __builtin_amdgcn_mfma_f32_16x16x32_bf16(a, b1, a1, 0, 0, 0);
      }
#pragma unroll
      for (int i = 0; i < 4; ++i) {
        int b = bi[i];
        float r0 = sigmoid_fast(a0[i] + br0 + gx0[i]);
        float r1 = sigmoid_fast(a1[i] + br1 + gx1[i]);
        float h0v = (float)hslot[b * HID + j0];   // L1-hot from A-frag pass
        float h1v = (float)hslot[b * HID + j1];
        rh_bf[b * HID + j0] = (bf16_t)(r0 * h0v);
        rh_bf[b * HID + j1] = (bf16_t)(r1 * h1v);
      }
      publish(&rfl[blk], (unsigned)(t + 1));
    }
  } else if (blk < NR + NZ) {
    // ============ ZH block: 32 cols of z, h_tilde, h_new ===================
    const int zb = blk - NR;
    const int c0 = zb * 32;
    for (int idx = tid; idx < 32 * HID; idx += 256) {
      int n = idx & 31, k = idx >> 5;
      Wbuf[n * LDSK + k]             = (bf16_t)Wz_h[k * HID + c0 + n];
      Wbuf[32 * LDSK + n * LDSK + k] = (bf16_t)Wh_h[k * HID + c0 + n];
    }
    __syncthreads();

    const int j0 = c0 + n16, j1 = j0 + 16;
    const float bz0 = b_z[j0], bz1 = b_z[j1];
    const float bh0 = b_h[j0], bh1 = b_h[j1];
    const bf16_t* wz0 = &Wbuf[n16 * LDSK + q * 8];
    const bf16_t* wz1 = &Wbuf[(16 + n16) * LDSK + q * 8];
    const bf16_t* wh0 = &Wbuf[32 * LDSK + n16 * LDSK + q * 8];
    const bf16_t* wh1 = &Wbuf[32 * LDSK + (16 + n16) * LDSK + q * 8];
    const bf16_t* rhrow = rh_bf + aoff;

    f32x4 hm0 = {0.f,0.f,0.f,0.f}, hm1 = {0.f,0.f,0.f,0.f};  // fp32 h master

    for (int t = 0; t < TLEN; ++t) {
      // ---- z phase (needs only h(t); overlaps R's work) ----
      wait32(hfl, (unsigned)t);
      int xb[4]; float gz0[4], gz1[4], gh0[4], gh1[4];
#pragma unroll
      for (int i = 0; i < 4; ++i) {
        xb[i]  = X[bi[i] * TLEN + t];
        gz0[i] = Wz_x[xb[i] * HID + j0];
        gz1[i] = Wz_x[xb[i] * HID + j1];
        gh0[i] = Wh_x[xb[i] * HID + j0];
        gh1[i] = Wh_x[xb[i] * HID + j1];
      }
      const bf16_t* hrow = h0 + (t & (NHB - 1)) * HBUF + aoff;
      f32x4 az0 = {0.f,0.f,0.f,0.f}, az1 = {0.f,0.f,0.f,0.f};
#pragma unroll 8
      for (int kk = 0; kk < 32; ++kk) {
        bf16x8 a  = *reinterpret_cast<const bf16x8*>(hrow + kk * 32);
        bf16x8 b0 = *reinterpret_cast<const bf16x8*>(wz0 + kk * 32);
        bf16x8 b1 = *reinterpret_cast<const bf16x8*>(wz1 + kk * 32);
        az0 = __builtin_amdgcn_mfma_f32_16x16x32_bf16(a, b0, az0, 0, 0, 0);
        az1 = __builtin_amdgcn_mfma_f32_16x16x32_bf16(a, b1, az1, 0, 0, 0);
      }
      f32x4 z0, z1;
#pragma unroll
      for (int i = 0; i < 4; ++i) {
        z0[i] = sigmoid_fast(az0[i] + bz0 + gz0[i]);
        z1[i] = sigmoid_fast(az1[i] + bz1 + gz1[i]);
      }

      // ---- h_tilde phase (needs full rh(t); WAR guard vs out heads) ----
      unsigned otgt = (t >= 3) ? (unsigned)(t - 3) : 0u;
      wait_rf_of(rfl, ofl, (unsigned)(t + 1), otgt);
      f32x4 ah0 = {0.f,0.f,0.f,0.f}, ah1 = {0.f,0.f,0.f,0.f};
#pragma unroll 8
      for (int kk = 0; kk < 32; ++kk) {
        bf16x8 a  = *reinterpret_cast<const bf16x8*>(rhrow + kk * 32);
        bf16x8 b0 = *reinterpret_cast<const bf16x8*>(wh0 + kk * 32);
        bf16x8 b1 = *reinterpret_cast<const bf16x8*>(wh1 + kk * 32);
        ah0 = __builtin_amdgcn_mfma_f32_16x16x32_bf16(a, b0, ah0, 0, 0, 0);
        ah1 = __builtin_amdgcn_mfma_f32_16x16x32_bf16(a, b1, ah1, 0, 0, 0);
      }
      bf16_t* hnext = h0 + ((t + 1) & (NHB - 1)) * HBUF;
#pragma unroll
      for (int i = 0; i < 4; ++i) {
        int b = bi[i];
        float ht0 = tanh_fast(ah0[i] + bh0 + gh0[i]);
        float ht1 = tanh_fast(ah1[i] + bh1 + gh1[i]);
        float hn0 = z0[i] * hm0[i] + (1.f - z0[i]) * ht0;
        float hn1 = z1[i] * hm1[i] + (1.f - z1[i]) * ht1;
        hm0[i] = hn0; hm1[i] = hn1;
        hnext[b * HID + j0] = (bf16_t)hn0;
        hnext[b * HID + j1] = (bf16_t)hn1;
      }
      publish(&hfl[zb], (unsigned)(t + 1));
    }
  } else {
    // ============ out head: out[t-1] = h_t @ W_o + b_o =====================
    const int ob = blk - NR - NZ;
    const int c0 = ob * 16;
    for (int idx = tid; idx < 16 * HID; idx += 256) {
      int n = idx & 15, k = idx >> 4;
      Wbuf[n * LDSK + k] = (bf16_t)W_o[k * VOC + c0 + n];
    }
    __syncthreads();

    const int v = c0 + n16;
    const float bos = b_o[v];
    const bf16_t* w0 = &Wbuf[n16 * LDSK + q * 8];

    for (int t = 1; t <= TLEN; ++t) {
      wait32(hfl, (unsigned)t);
      const bf16_t* hrow = h0 + (t & (NHB - 1)) * HBUF + aoff;
      f32x4 acc = {0.f,0.f,0.f,0.f};
#pragma unroll 8
      for (int kk = 0; kk < 32; ++kk) {
        bf16x8 a = *reinterpret_cast<const bf16x8*>(hrow + kk * 32);
        bf16x8 b = *reinterpret_cast<const bf16x8*>(w0 + kk * 32);
        acc = __builtin_amdgcn_mfma_f32_16x16x32_bf16(a, b, acc, 0, 0, 0);
      }
#pragma unroll
      for (int i = 0; i < 4; ++i) {
        int b = bi[i];
        out[(b * TLEN + (t - 1)) * VOC + v] = acc[i] + bos;
      }
      publish(&ofl[ob], (unsigned)t);  // h_t reads drained by publish's barrier
    }
  }
}

extern "C" void kernel_launch(void* const* d_in, const int* in_sizes, int n_in,
                              void* d_out, int out_size, void* d_ws, size_t ws_size,
                              hipStream_t stream) {
  const int*   X    = (const int*)d_in[0];
  const float* Wr_x = (const float*)d_in[1];
  const float* Wr_h = (const float*)d_in[2];
  const float* b_r  = (const float*)d_in[3];
  const float* Wz_x = (const float*)d_in[4];
  const float* Wz_h = (const float*)d_in[5];
  const float* b_z  = (const float*)d_in[6];
  const float* Wh_x = (const float*)d_in[7];
  const float* Wh_h = (const float*)d_in[8];
  const float* b_h  = (const float*)d_in[9];
  const float* W_o  = (const float*)d_in[10];
  const float* b_o  = (const float*)d_in[11];

  char* ws = (char*)d_ws;
  // layout: [flags 4KB | h 4 x 128KB | rh 128KB]
  unsigned* flags = (unsigned*)ws;
  bf16_t*   h0    = (bf16_t*)(ws + 4096);
  bf16_t*   rh_bf = (bf16_t*)(ws + 4096 + NHB * HBUF * sizeof(bf16_t));

  // zero flags + h slot 0 (h(0)=0); rh and slots 1..3 written before read
  hipMemsetAsync(ws, 0, 4096 + HBUF * sizeof(bf16_t), stream);

  gru_split<<<NBLK, 256, 0, stream>>>(
      X, Wr_x, Wr_h, b_r, Wz_x, Wz_h, b_z, Wh_x, Wh_h, b_h, W_o, b_o,
      (float*)d_out, h0, rh_bf, flags);
}